// Round 6
// baseline (174.241 us; speedup 1.0000x reference)
//
#include <hip/hip_runtime.h>
#include <hip/hip_bf16.h>
#include <cstddef>

#define NNODE 4096
#define INF   512
#define OUTF  256
#define HID   8
#define CAP   128   // max degree; Binomial(4096,0.01) max ~67; padded to mult-of-16, <=80

typedef __attribute__((ext_vector_type(8))) short short8;
typedef __attribute__((ext_vector_type(4))) float f32x4;

__device__ __forceinline__ unsigned short f2bf(float f){
  unsigned int u = __float_as_uint(f);
  u += 0x7fffu + ((u >> 16) & 1u);   // round-to-nearest-even
  return (unsigned short)(u >> 16);
}
__device__ __forceinline__ float bf2f(unsigned short s){
  return __uint_as_float((unsigned int)s << 16);
}

// 2-deep software-pipelined gather: LOAD issues 8 wave-loads (16 neighbors,
// 2 per lane-half), CONS converts+accumulates.  Steady state keeps 16 loads
// in flight per wave (compiler emits counted vmcnt(8) between batches).
#define HOP_LOAD(buf, b) { int _o = (b) * 16 + half;                          \
  _Pragma("unroll") for (int t = 0; t < 8; t++){                              \
    int _j = cl[_o + 2 * t];                                                  \
    buf[t] = *(const short8*)(src + (size_t)_j * instride); } }
#define HOP_CONS(buf) { _Pragma("unroll") for (int t = 0; t < 8; t++)         \
  _Pragma("unroll") for (int e = 0; e < 8; e++)                               \
    acc[e] += bf2f((unsigned short)buf[t][e]); }
#define HOP_PIPE() {                                                          \
  if (nb > 0){                                                                \
    HOP_LOAD(pA, 0);                                                          \
    int i = 1;                                                                \
    for (; i + 1 < nb; i += 2){                                               \
      HOP_LOAD(pB, i);                                                        \
      HOP_CONS(pA);                                                           \
      HOP_LOAD(pA, i + 1);                                                    \
      HOP_CONS(pB);                                                           \
    }                                                                         \
    if (i < nb){ HOP_LOAD(pB, i); HOP_CONS(pA); HOP_CONS(pB); }               \
    else { HOP_CONS(pA); }                                                    \
  } }

// ================================================================ dispatch 1
// FRONT: build_csr (blocks 0..4095) + gat_h (4096..5119) + convert_w (5120..6143)
// all three are mutually independent (adj->csr; x->h,dstv,xb; Wsgc->wbT,+pads)
__global__ __launch_bounds__(256) void front(const float* __restrict__ adj,
                                             int* __restrict__ deg,
                                             int* __restrict__ cols,
                                             const float* __restrict__ x,
                                             const float* __restrict__ W1,
                                             const float* __restrict__ a1,
                                             float* __restrict__ h,
                                             float* __restrict__ dstv,
                                             unsigned short* __restrict__ xb,
                                             const float* __restrict__ Wsgc,
                                             unsigned short* __restrict__ wbT,
                                             unsigned short* __restrict__ Gb,
                                             unsigned short* __restrict__ T1,
                                             unsigned short* __restrict__ T2){
  __shared__ int cnt;
  int bid = blockIdx.x, tid = threadIdx.x;
  int lane = tid & 63;

  if (bid < NNODE){
    // ---- CSR build: one block per row.  Wave-aggregated allocation: shfl_up
    // inclusive scan of per-thread nonzero count, ONE LDS atomic per wave per
    // iter (kills same-address LDS-atomic serialization).  Rows PADDED to a
    // multiple of 16 with index NNODE (zeroed row in every gather source).
    int row = bid;
    if (tid == 0) cnt = 0;
    __syncthreads();
    const float4* arow = (const float4*)(adj + (size_t)row * NNODE);
    int* crow = cols + (size_t)row * CAP;
    #pragma unroll
    for (int k = 0; k < 4; k++){
      int idx = k * 256 + tid;          // float4 index
      float4 v = arow[idx];
      int n0 = (v.x != 0.f), n1 = (v.y != 0.f), n2 = (v.z != 0.f), n3 = (v.w != 0.f);
      int m = n0 + n1 + n2 + n3;
      int pre = m;
      #pragma unroll
      for (int o = 1; o < 64; o <<= 1){
        int t = __shfl_up(pre, o, 64);
        if (lane >= o) pre += t;
      }
      int wtot = __shfl(pre, 63, 64);
      int base = 0;
      if (lane == 63 && wtot) base = atomicAdd(&cnt, wtot);
      base = __shfl(base, 63, 64);
      int o = base + pre - m;           // exclusive prefix within wave
      int c = idx * 4;
      if (n0){ if (o < CAP) crow[o] = c;     o++; }
      if (n1){ if (o < CAP) crow[o] = c + 1; o++; }
      if (n2){ if (o < CAP) crow[o] = c + 2; o++; }
      if (n3){ if (o < CAP) crow[o] = c + 3; }
    }
    __syncthreads();
    int c = cnt > CAP ? CAP : cnt;
    int c16 = (c + 15) & ~15;
    if (c16 == 0) c16 = 16;             // degree-0 guard (P ~ e^-41, but safe)
    if (c16 > CAP) c16 = CAP;
    if (tid < c16 - c) crow[c + tid] = NNODE;   // pad with zero-row index
    if (tid == 0) deg[row] = c16;

  } else if (bid < NNODE + 1024){
    // ---- gat_h: h = x @ W1, dstv = h . a1[8:16]; one wave per row.
    // Vectorized: lane owns k in [lane*8, lane*8+8): float4x2 read, short8
    // xb store (G13 — scalar bf16 stores were 2-2.5x slower).
    int b2 = bid - NNODE;
    if (b2 == 0 && tid < HID) h[(size_t)NNODE * HID + tid] = 0.f;  // pad row
    int wave = tid >> 6;
    int row = b2 * 4 + wave;
    const float* xr8 = x + (size_t)row * INF + lane * 8;
    float4 v0 = ((const float4*)xr8)[0];
    float4 v1 = ((const float4*)xr8)[1];
    float xv[8] = {v0.x, v0.y, v0.z, v0.w, v1.x, v1.y, v1.z, v1.w};
    union { short8 v; unsigned short u[8]; } pk;
    #pragma unroll
    for (int u = 0; u < 8; u++) pk.u[u] = f2bf(xv[u]);
    *(short8*)(xb + (size_t)row * INF + lane * 8) = pk.v;
    float acc[HID];
    #pragma unroll
    for (int f = 0; f < HID; f++) acc[f] = 0.f;
    #pragma unroll
    for (int u = 0; u < 8; u++){
      const float* wp = W1 + (size_t)(lane * 8 + u) * HID;
      #pragma unroll
      for (int f = 0; f < HID; f++) acc[f] += xv[u] * wp[f];
    }
    #pragma unroll
    for (int f = 0; f < HID; f++)
      for (int o = 32; o >= 1; o >>= 1) acc[f] += __shfl_xor(acc[f], o, 64);
    if (lane == 0){
      float d = 0.f;
      #pragma unroll
      for (int f = 0; f < HID; f++){ h[(size_t)row*HID + f] = acc[f]; d += acc[f] * a1[HID + f]; }
      dstv[row] = d;
    }

  } else {
    // ---- convert_w: wbT[c][k] = bf16(W'[k][c]); + zero pad rows of Gb/T1/T2
    int idx = (bid - NNODE - 1024) * 256 + tid;   // 0 .. 262143
    if (idx < 512) Gb[(size_t)NNODE * 512 + idx] = 0;
    if (idx < 256){ T1[(size_t)NNODE * 256 + idx] = 0; T2[(size_t)NNODE * 256 + idx] = 0; }
    int c = idx >> 9, k = idx & 511;
    float val = (c < 256) ? Wsgc[(size_t)k * OUTF + c]
                          : Wsgc[(size_t)(1024 + k) * OUTF + (c - 256)];
    wbT[idx] = f2bf(val);
  }
}

// ================================================================ dispatch 2
// MID: gemm_xw (blocks 0..127, issued first — the long pole) + gat_agg1 with
// inline softmax-p prologue (blocks 128..1151).  Independent: gemm xb,wbT->Gb;
// agg h,dstv,cols->h2.
__global__ __launch_bounds__(256) void mid(const unsigned short* __restrict__ XB,
                                           const unsigned short* __restrict__ BT,
                                           unsigned short* __restrict__ Gb,
                                           const float* __restrict__ h,
                                           const float* __restrict__ dstv,
                                           const int* __restrict__ deg,
                                           const int* __restrict__ cols,
                                           const float* __restrict__ W2,
                                           float* __restrict__ h2){
  __shared__ union {
    struct { unsigned short As[128][72]; unsigned short Bs[128][72]; } g;  // 36 KB
    struct { float p[NNODE + 1]; float red[4]; } a;                        // 16.4 KB
  } sm;
  int bid = blockIdx.x, tid = threadIdx.x;
  int wave = tid >> 6, lane = tid & 63;

  if (bid < 128){
    // ---- bf16 MFMA GEMM: Gb[4096][512](bf16) = xb @ W'.  128x128 tile,
    // 4 waves 2x2, wave = 4x4 of 16x16x32 MFMAs, BK=64, bf16 epilogue.
    int bx = bid & 31, by = bid >> 5;
    int row0 = bx * 128, col0 = by * 128;
    int wr = wave >> 1, wc = wave & 1;
    f32x4 acc[4][4];
    #pragma unroll
    for (int i = 0; i < 4; i++)
      #pragma unroll
      for (int j = 0; j < 4; j++)
        #pragma unroll
        for (int e = 0; e < 4; e++) acc[i][j][e] = 0.f;
    int mrow = lane & 15;
    int kq = (lane >> 4) * 8;
    for (int k0 = 0; k0 < 512; k0 += 64){
      #pragma unroll
      for (int ps = 0; ps < 4; ps++){
        int idx = ps * 256 + tid;
        int r = idx >> 3;
        int ko = (idx & 7) * 8;
        *(int4*)(&sm.g.As[r][ko]) = *(const int4*)(XB + ((size_t)(row0 + r) * 512 + k0 + ko));
        *(int4*)(&sm.g.Bs[r][ko]) = *(const int4*)(BT + ((size_t)(col0 + r) * 512 + k0 + ko));
      }
      __syncthreads();
      #pragma unroll
      for (int kk = 0; kk < 2; kk++){
        short8 a[4], b[4];
        #pragma unroll
        for (int i = 0; i < 4; i++)
          a[i] = *(const short8*)(&sm.g.As[wr * 64 + i * 16 + mrow][kk * 32 + kq]);
        #pragma unroll
        for (int j = 0; j < 4; j++)
          b[j] = *(const short8*)(&sm.g.Bs[wc * 64 + j * 16 + mrow][kk * 32 + kq]);
        #pragma unroll
        for (int i = 0; i < 4; i++)
          #pragma unroll
          for (int j = 0; j < 4; j++)
            acc[i][j] = __builtin_amdgcn_mfma_f32_16x16x32_bf16(a[i], b[j], acc[i][j], 0, 0, 0);
      }
      __syncthreads();
    }
    int crow = (lane >> 4) * 4;   // C/D: col = lane&15, row = (lane>>4)*4 + reg
    int ccol = lane & 15;
    #pragma unroll
    for (int i = 0; i < 4; i++)
      #pragma unroll
      for (int j = 0; j < 4; j++)
        #pragma unroll
        for (int e = 0; e < 4; e++){
          int r = row0 + wr * 64 + i * 16 + crow + e;
          int c = col0 + wc * 64 + j * 16 + ccol;
          Gb[(size_t)r * 512 + c] = f2bf(acc[i][j][e]);
        }

  } else {
    // ---- gat_agg1 with inline softmax-p prologue (p in LDS, per block).
    if (tid == 0) sm.a.p[NNODE] = 0.f;            // zero pad entry
    float mx = -INFINITY;
    for (int i = tid; i < NNODE; i += 256) mx = fmaxf(mx, dstv[i]);
    #pragma unroll
    for (int o = 32; o >= 1; o >>= 1) mx = fmaxf(mx, __shfl_xor(mx, o, 64));
    if (lane == 0) sm.a.red[wave] = mx;
    __syncthreads();
    mx = fmaxf(fmaxf(sm.a.red[0], sm.a.red[1]), fmaxf(sm.a.red[2], sm.a.red[3]));
    __syncthreads();
    float sum = 0.f;
    for (int i = tid; i < NNODE; i += 256){ float e = expf(dstv[i] - mx); sm.a.p[i] = e; sum += e; }
    #pragma unroll
    for (int o = 32; o >= 1; o >>= 1) sum += __shfl_xor(sum, o, 64);
    if (lane == 0) sm.a.red[wave] = sum;
    __syncthreads();
    float inv = 1.0f / (sm.a.red[0] + sm.a.red[1] + sm.a.red[2] + sm.a.red[3]);
    for (int i = tid; i < NNODE; i += 256) sm.a.p[i] *= inv;
    __syncthreads();

    int row = (bid - 128) * 4 + wave;
    const int* cl = cols + (size_t)row * CAP;
    int d = deg[row];
    int ng = lane >> 3;      // neighbor group 0..7
    int f  = lane & 7;       // feature 0..7
    float acc = 0.f;
    for (int n = ng; n < d; n += 8){
      int j = cl[n];         // pad j=NNODE: p=0, h row zeroed -> adds 0
      acc += sm.a.p[j] * h[(size_t)j * HID + f];
    }
    acc += __shfl_xor(acc, 8, 64);
    acc += __shfl_xor(acc, 16, 64);
    acc += __shfl_xor(acc, 32, 64);
    float e = acc > 0.f ? acc : expm1f(acc);
    float t = e * W2[f];
    t += __shfl_xor(t, 1, 64);
    t += __shfl_xor(t, 2, 64);
    t += __shfl_xor(t, 4, 64);
    if (lane == 0) h2[row] = t;
  }
}

// ================================================================ dispatch 3
// SC_HOP1: hop1 T1 = adj @ Gright (blocks 0..1023, pipelined gather) +
// scores/mask with inline softmax-q prologue (blocks 1024..2047).
__global__ __launch_bounds__(256, 4) void sc_hop1(const unsigned short* __restrict__ Gb,
                                                  unsigned short* __restrict__ T1,
                                                  const float* __restrict__ h2,
                                                  const float* __restrict__ a2,
                                                  const int* __restrict__ deg,
                                                  const int* __restrict__ cols,
                                                  float* __restrict__ maskf){
  __shared__ float q[NNODE + 1];
  __shared__ float red[4];
  int bid = blockIdx.x, tid = threadIdx.x;
  int wave = tid >> 6, lane = tid & 63;

  if (bid < 1024){
    // ---- hop1: wave = 2 neighbors x 32 col-chunks of Gb[:, 256:512]
    int row = bid * 4 + wave;
    const int* cl = cols + (size_t)row * CAP;
    int nb = deg[row] >> 4;
    int half = lane >> 5, cid = lane & 31;
    const int instride = 512;
    const unsigned short* src = Gb + 256 + cid * 8;
    float acc[8];
    #pragma unroll
    for (int e = 0; e < 8; e++) acc[e] = 0.f;
    short8 pA[8], pB[8];
    HOP_PIPE();
    #pragma unroll
    for (int e = 0; e < 8; e++) acc[e] += __shfl_xor(acc[e], 32, 64);
    if (half == 0){
      union { short8 v; unsigned short u[8]; } pk;
      #pragma unroll
      for (int e = 0; e < 8; e++) pk.u[e] = f2bf(acc[e]);
      *(short8*)(T1 + (size_t)row * OUTF + cid * 8) = pk.v;
    }

  } else {
    // ---- scores/mask with inline softmax-q prologue (q in LDS).
    float s2 = a2[1];
    if (tid == 0) q[NNODE] = 0.f;                 // zero pad entry
    float mx = -INFINITY;
    for (int i = tid; i < NNODE; i += 256) mx = fmaxf(mx, s2 * h2[i]);
    #pragma unroll
    for (int o = 32; o >= 1; o >>= 1) mx = fmaxf(mx, __shfl_xor(mx, o, 64));
    if (lane == 0) red[wave] = mx;
    __syncthreads();
    mx = fmaxf(fmaxf(red[0], red[1]), fmaxf(red[2], red[3]));
    __syncthreads();
    float sum = 0.f;
    for (int i = tid; i < NNODE; i += 256){ float e = expf(s2 * h2[i] - mx); q[i] = e; sum += e; }
    #pragma unroll
    for (int o = 32; o >= 1; o >>= 1) sum += __shfl_xor(sum, o, 64);
    if (lane == 0) red[wave] = sum;
    __syncthreads();
    float inv = 1.0f / (red[0] + red[1] + red[2] + red[3]);
    for (int i = tid; i < NNODE; i += 256) q[i] = q[i] * inv * h2[i];
    __syncthreads();

    int row = (bid - 1024) * 4 + wave;
    const int* cl = cols + (size_t)row * CAP;
    int d = deg[row];
    float s = 0.f;
    for (int n = lane; n < d; n += 64) s += q[cl[n]];   // pad -> q[NNODE]=0
    #pragma unroll
    for (int o = 32; o >= 1; o >>= 1) s += __shfl_xor(s, o, 64);
    if (lane == 0){
      float e = s > 0.f ? s : expm1f(s);
      maskf[row] = (e > 0.7f) ? 1.0f : 0.0f;
    }
  }
}

// ================================================================ dispatch 4
// hop2: T2 = adj @ T1 (bf16, full — T2[j] is consumed for all neighbors of
// mask-0 rows, so NO mask early-out is legal here).  Pipelined gather.
__global__ __launch_bounds__(256, 4) void hop_bf(const unsigned short* __restrict__ in,
                                                 int instride, int colbase,
                                                 unsigned short* __restrict__ out,
                                                 const int* __restrict__ deg,
                                                 const int* __restrict__ cols){
  int wave = threadIdx.x >> 6, lane = threadIdx.x & 63;
  int row = blockIdx.x * 4 + wave;
  const int* cl = cols + (size_t)row * CAP;
  int nb = deg[row] >> 4;
  int half = lane >> 5, cid = lane & 31;
  const unsigned short* src = in + colbase + cid * 8;
  float acc[8];
  #pragma unroll
  for (int e = 0; e < 8; e++) acc[e] = 0.f;
  short8 pA[8], pB[8];
  HOP_PIPE();
  #pragma unroll
  for (int e = 0; e < 8; e++) acc[e] += __shfl_xor(acc[e], 32, 64);
  if (half == 0){
    union { short8 v; unsigned short u[8]; } pk;
    #pragma unroll
    for (int e = 0; e < 8; e++) pk.u[e] = f2bf(acc[e]);
    *(short8*)(out + (size_t)row * OUTF + cid * 8) = pk.v;
  }
}

// ================================================================ dispatch 5
// final hop + epilogue with per-row pruning: mask=1 rows gather Gb[:, :256],
// mask=0 rows gather T2.  fp32 output + bias.  Pipelined gather.
__global__ __launch_bounds__(256, 4) void hop_final_bf(const unsigned short* __restrict__ Gb,
                                                       const unsigned short* __restrict__ T2,
                                                       const float* __restrict__ maskf,
                                                       const float* __restrict__ b,
                                                       float* __restrict__ out,
                                                       const int* __restrict__ deg,
                                                       const int* __restrict__ cols){
  int wave = threadIdx.x >> 6, lane = threadIdx.x & 63;
  int row = blockIdx.x * 4 + wave;
  const int* cl = cols + (size_t)row * CAP;
  int nb = deg[row] >> 4;
  bool m = maskf[row] != 0.0f;             // wave-uniform
  const unsigned short* base = m ? Gb : T2;
  int instride = m ? 512 : 256;
  int half = lane >> 5, cid = lane & 31;
  const unsigned short* src = base + cid * 8;
  float acc[8];
  #pragma unroll
  for (int e = 0; e < 8; e++) acc[e] = 0.f;
  short8 pA[8], pB[8];
  HOP_PIPE();
  #pragma unroll
  for (int e = 0; e < 8; e++) acc[e] += __shfl_xor(acc[e], 32, 64);
  if (half == 0){
    f32x4 b0 = ((const f32x4*)(b + cid * 8))[0];
    f32x4 b1 = ((const f32x4*)(b + cid * 8 + 4))[0];
    f32x4 o0, o1;
    #pragma unroll
    for (int e = 0; e < 4; e++){ o0[e] = acc[e] + b0[e]; o1[e] = acc[4 + e] + b1[e]; }
    float* orow = out + (size_t)row * OUTF + cid * 8;
    ((f32x4*)orow)[0] = o0;
    ((f32x4*)(orow + 4))[0] = o1;
  }
}

extern "C" void kernel_launch(void* const* d_in, const int* in_sizes, int n_in,
                              void* d_out, int out_size, void* d_ws, size_t ws_size,
                              hipStream_t stream) {
  const float* x    = (const float*)d_in[0];
  const float* adj  = (const float*)d_in[1];
  const float* W1   = (const float*)d_in[2];
  const float* a1   = (const float*)d_in[3];
  const float* W2   = (const float*)d_in[4];
  const float* a2   = (const float*)d_in[5];
  const float* Wsgc = (const float*)d_in[6];
  const float* bsgc = (const float*)d_in[7];
  float* out = (float*)d_out;

  char* w = (char*)d_ws;
  size_t off = 0;
  auto carve = [&](size_t bytes) -> char* {
    char* p = w + off;
    off += (bytes + 255) & ~(size_t)255;
    return p;
  };
  int*   deg   = (int*)carve((size_t)NNODE * 4);
  int*   cols  = (int*)carve((size_t)NNODE * CAP * 4);
  float* h     = (float*)carve((size_t)(NNODE + 1) * HID * 4);
  float* dstv  = (float*)carve((size_t)NNODE * 4);
  float* h2    = (float*)carve((size_t)NNODE * 4);
  float* maskf = (float*)carve((size_t)NNODE * 4);
  unsigned short* wbT = (unsigned short*)carve((size_t)512 * 512 * 2);
  unsigned short* xb  = (unsigned short*)carve((size_t)NNODE * INF * 2);
  unsigned short* Gb  = (unsigned short*)carve((size_t)(NNODE + 1) * 512 * 2);
  unsigned short* T1  = (unsigned short*)carve((size_t)(NNODE + 1) * OUTF * 2);
  unsigned short* T2  = (unsigned short*)carve((size_t)(NNODE + 1) * OUTF * 2);

  // D1: csr (scan-compaction) + gat_h(+xb, vectorized) + convert_w
  front<<<NNODE + 1024 + 1024, 256, 0, stream>>>(adj, deg, cols,
                                                 x, W1, a1, h, dstv, xb,
                                                 Wsgc, wbT, Gb, T1, T2);
  // D2: gemm (first 128 blocks) + agg1-with-softmax-prologue (next 1024)
  mid<<<128 + 1024, 256, 0, stream>>>(xb, wbT, Gb, h, dstv, deg, cols, W2, h2);
  // D3: hop1 (first 1024 blocks, 2-deep pipelined) + scores (next 1024)
  sc_hop1<<<2048, 256, 0, stream>>>(Gb, T1, h2, a2, deg, cols, maskf);
  // D4: T2 = adj @ T1  (full — T2 consumed for all neighbors of mask-0 rows)
  hop_bf<<<NNODE / 4, 256, 0, stream>>>(T1, 256, 0, T2, deg, cols);
  // D5: final hop, per-row pruned source select + bias
  hop_final_bf<<<NNODE / 4, 256, 0, stream>>>(Gb, T2, maskf, bsgc, out, deg, cols);
}